// Round 10
// baseline (265.759 us; speedup 1.0000x reference)
//
#include <hip/hip_runtime.h>
#include <math.h>

#define UNITS 64
#define TT 100
#define NB 16          // batch rows per workgroup = one MFMA M-tile
#define NTH 256        // 4 waves; wave w owns unit-columns [16w,16w+16) for all 4 gates
#define HSTR 72        // hbuf row stride in halves
#define NCHUNK 64      // prologue chunks (256 rows each)

typedef _Float16 half8 __attribute__((ext_vector_type(8)));
typedef float floatx4 __attribute__((ext_vector_type(4)));

#define LOG2E 1.44269504088896f

__device__ __forceinline__ float rcp_fast(float x) { return __builtin_amdgcn_rcpf(x); }
__device__ __forceinline__ float exp2_fast(float x) { return __builtin_amdgcn_exp2f(x); }

__device__ __forceinline__ float fast_sigmoid(float x) {
    return rcp_fast(1.0f + exp2_fast(-LOG2E * x));      // saturates correctly
}
__device__ __forceinline__ float fast_tanh(float x) {
    return __builtin_fmaf(2.0f, rcp_fast(1.0f + exp2_fast(-2.0f * LOG2E * x)), -1.0f);
}

// ---- prologue (single node): lengths + per-chunk histograms, no atomics/memset ----
// Block bi owns rows [256*bi, 256*bi+256). histT[l*64+bi] = #rows of length l in chunk.
__global__ __launch_bounds__(256) void len_hist_kernel(
    const float* __restrict__ x, int* __restrict__ len, int* __restrict__ histT, int B)
{
    __shared__ int lh[TT + 1];
    const int tid = threadIdx.x;
    const int bi  = blockIdx.x;
    const int grp = tid >> 4;   // row within pass
    const int sub = tid & 15;   // lane within row

    for (int i = tid; i <= TT; i += 256) lh[i] = 0;
    __syncthreads();

    for (int pass = 0; pass < 16; ++pass) {
        const int row = bi * 256 + pass * 16 + grp;
        if (row < B) {
            const float* xp = x + (size_t)row * (TT * 3);
            int m = 0;
            for (int t = sub; t < TT; t += 16) {    // 16 lanes x 12B contiguous
                const float a = xp[3*t], b = xp[3*t+1], c = xp[3*t+2];
                if (a != 0.0f || b != 0.0f || c != 0.0f) m = t + 1;
            }
            #pragma unroll
            for (int off = 8; off; off >>= 1) m = max(m, __shfl_down(m, off, 16));
            if (sub == 0) { len[row] = m; atomicAdd(&lh[m], 1); }   // LDS atomic only
        }
    }
    __syncthreads();
    for (int i = tid; i <= TT; i += 256) histT[i * NCHUNK + bi] = lh[i];
}

__global__ __launch_bounds__(NTH, 4) void lstm_kernel(
    const float* __restrict__ x,    // (B,100,3)
    const float* __restrict__ W,    // (3,256)
    const float* __restrict__ U,    // (64,256)
    const float* __restrict__ bias, // (256,)
    const float* __restrict__ W1,   // (64,64)
    const float* __restrict__ b1,   // (64,)
    const float* __restrict__ W2,   // (64,5)
    const float* __restrict__ b2,   // (5,)
    const int* __restrict__ lenArr, // (B,) per-row lengths (may be null)
    const int* __restrict__ histT,  // (101*64,) per-chunk length counts (may be null)
    float* __restrict__ out, int B)
{
    __shared__ __align__(16) _Float16 hb[2][NB * HSTR];   // double-buffered h (f16)
    __shared__ int s_hist[TT + 1];
    __shared__ int s_offs[TT + 1];
    __shared__ int shInt[2 * NB];                         // rows / lengths for this tile
    __shared__ float h1buf[NB * 64];
    __shared__ float logitbuf[NB * 5];

    const int tid = threadIdx.x;
    const int w   = tid >> 6;
    const int l   = tid & 63;
    const int q   = l >> 4;
    const int cnl = l & 15;
    const int b0  = blockIdx.x * NB;

    // ===== in-block rank->row reconstruction (deterministic, read-only) =====
    if (histT) {
        for (int i = tid; i <= TT; i += NTH) {            // total hist
            int s = 0;
            #pragma unroll 8
            for (int pb = 0; pb < NCHUNK; ++pb) s += histT[i * NCHUNK + pb];
            s_hist[i] = s;
        }
        __syncthreads();
        for (int i = tid; i <= TT; i += NTH) {            // descending-length offsets
            int s = 0;
            for (int k = i + 1; k <= TT; ++k) s += s_hist[k];
            s_offs[i] = s;
        }
        __syncthreads();
        if (tid < NB) {
            const int r = b0 + tid;                       // my global rank
            int lg = TT;                                  // find length group
            for (; lg > 0; --lg)
                if (r >= s_offs[lg] && r < s_offs[lg] + s_hist[lg]) break;
            int j = r - s_offs[lg];                       // ordinal within group
            int pb = 0, cum = 0;                          // find chunk
            for (; pb < NCHUNK - 1; ++pb) {
                const int c = histT[lg * NCHUNK + pb];
                if (cum + c > j) break;
                cum += c;
            }
            int need = j - cum, row = pb * 256;           // scan chunk for ordinal match
            for (int i = 0; i < 256; ++i) {
                const int b = pb * 256 + i;
                if (b < B && lenArr[b] == lg) {
                    if (need == 0) { row = b; break; }
                    --need;
                }
            }
            row = (row < 0) ? 0 : ((row >= B) ? (B - 1) : row);
            shInt[tid] = row;
            shInt[NB + tid] = lg;
        }
    } else {
        if (tid < NB) { shInt[tid] = b0 + tid; shInt[NB + tid] = TT; }
    }
    for (int i = tid; i < NB * HSTR; i += NTH) hb[0][i] = (_Float16)0.0f;
    __syncthreads();   // shInt visible before ANY reader (round-7 lesson)

    int maxlen = shInt[NB];           // descending sort -> rank b0 is tile max
    maxlen = (maxlen < 0) ? 0 : ((maxlen > TT) ? TT : maxlen);
    int rl[4];
    #pragma unroll
    for (int r = 0; r < 4; ++r) rl[r] = shInt[NB + 4*q + r];

    // ---- one-time preload: extended-K B fragments. Rows 0..63=U, 64..66=W,
    // 67=bias, 68..95=0.  B-frag (16x16x32): lane holds B[k=32kb+8q+j][zc].
    half8 Bf[4][3];
    #pragma unroll
    for (int g = 0; g < 4; ++g) {
        const int zc = 64 * g + 16 * w + cnl;
        #pragma unroll
        for (int kb = 0; kb < 3; ++kb)
            #pragma unroll
            for (int j = 0; j < 8; ++j) {
                const int k = 32 * kb + 8 * q + j;
                float v = 0.0f;
                if (k < 64)       v = U[k * 256 + zc];
                else if (k < 67)  v = W[(k - 64) * 256 + zc];
                else if (k == 67) v = bias[zc];
                Bf[g][kb][j] = (_Float16)v;
            }
    }

    // ---- per-lane x source: lane m=cnl reads row shInt[cnl] directly (L1-hot) ----
    const float* xp = x + (size_t)shInt[cnl] * (TT * 3);
    const bool isq0 = (q == 0);
    float px0 = 0.0f, px1 = 0.0f, px2 = 0.0f;
    if (isq0 && maxlen > 0) { px0 = xp[0]; px1 = xp[1]; px2 = xp[2]; }

    float c4[4] = {0.0f, 0.0f, 0.0f, 0.0f};
    _Float16 hcur[4] = {(_Float16)0.0f, (_Float16)0.0f, (_Float16)0.0f, (_Float16)0.0f};
    const floatx4 zero4 = {0.0f, 0.0f, 0.0f, 0.0f};

    __syncthreads();   // hb[0] zero visible

    #pragma unroll 1
    for (int t = 0; t < maxlen; ++t) {
        const _Float16* hbc = hb[t & 1];
        _Float16*       hbn = hb[(t + 1) & 1];

        // A fragments: lane holds A[m=cnl][k = 32*kb + 8q + j]
        const half8 A0 = *(const half8*)&hbc[cnl * HSTR + 8 * q];
        const half8 A1 = *(const half8*)&hbc[cnl * HSTR + 32 + 8 * q];
        const _Float16 z16 = (_Float16)0.0f;
        const half8 AX = { isq0 ? (_Float16)px0 : z16,
                           isq0 ? (_Float16)px1 : z16,
                           isq0 ? (_Float16)px2 : z16,
                           isq0 ? (_Float16)1.0f : z16,
                           z16, z16, z16, z16 };

        // prefetch x(t+1) (registers; latency hidden by MFMA/activation)
        if (isq0 && t + 1 < maxlen) {
            const float* xq = xp + 3 * (t + 1);
            px0 = xq[0]; px1 = xq[1]; px2 = xq[2];
        }

        floatx4 acc[4];
        #pragma unroll
        for (int g = 0; g < 4; ++g) {
            acc[g] = __builtin_amdgcn_mfma_f32_16x16x32_f16(AX, Bf[g][2], zero4, 0, 0, 0);
            acc[g] = __builtin_amdgcn_mfma_f32_16x16x32_f16(A0, Bf[g][0], acc[g], 0, 0, 0);
            acc[g] = __builtin_amdgcn_mfma_f32_16x16x32_f16(A1, Bf[g][1], acc[g], 0, 0, 0);
        }

        #pragma unroll
        for (int r = 0; r < 4; ++r) {
            const bool live = (t < rl[r]);   // mask == (t < len): interior all-zero x measure 0
            const float iv = fast_sigmoid(acc[0][r]);
            const float fv = fast_sigmoid(acc[1][r]);
            const float gv = fast_tanh  (acc[2][r]);
            const float ov = fast_sigmoid(acc[3][r]);
            const float cn = fv * c4[r] + iv * gv;
            c4[r] = live ? cn : c4[r];
            const _Float16 hn = (_Float16)(ov * fast_tanh(cn));
            hcur[r] = live ? hn : hcur[r];
            hbn[(4 * q + r) * HSTR + 16 * w + cnl] = hcur[r];
        }
        __syncthreads();   // single barrier: hbn visible; hbc (next hbn) safe to overwrite
    }

    const _Float16* hbL = hb[maxlen & 1];

    // ---- epilogue: h1 = relu(h @ W1 + b1) ----
    {
        const int j  = tid & 63;
        const int bb = tid >> 6;
        const float bj = b1[j];
        #pragma unroll
        for (int p = 0; p < NB / 4; ++p) {
            const int b = p * 4 + bb;
            float acc = bj;
            #pragma unroll 8
            for (int k = 0; k < UNITS; ++k)
                acc += (float)hbL[b * HSTR + k] * W1[k * 64 + j];
            h1buf[b * 64 + j] = fmaxf(acc, 0.0f);
        }
    }
    __syncthreads();

    if (tid < NB * 5) {
        const int b = tid / 5, s = tid % 5;
        float acc = b2[s];
        for (int j = 0; j < 64; ++j)
            acc += h1buf[b * 64 + j] * W2[j * 5 + s];
        logitbuf[b * 5 + s] = acc;
    }
    __syncthreads();

    if (tid < NB) {
        const int gb = shInt[tid];
        const float l0 = logitbuf[tid * 5 + 0];
        const float l1 = logitbuf[tid * 5 + 1];
        const float l2 = logitbuf[tid * 5 + 2];
        const float l3 = logitbuf[tid * 5 + 3];
        const float l4 = logitbuf[tid * 5 + 4];
        const float m  = fmaxf(fmaxf(fmaxf(l0, l1), fmaxf(l2, l3)), l4);
        const float e0 = __expf(l0 - m), e1 = __expf(l1 - m), e2 = __expf(l2 - m);
        const float e3 = __expf(l3 - m), e4 = __expf(l4 - m);
        const float rs = 1.0f / (e0 + e1 + e2 + e3 + e4);
        out[(size_t)gb * 5 + 0] = e0 * rs;
        out[(size_t)gb * 5 + 1] = e1 * rs;
        out[(size_t)gb * 5 + 2] = e2 * rs;
        out[(size_t)gb * 5 + 3] = e3 * rs;
        out[(size_t)gb * 5 + 4] = e4 * rs;
    }
}

extern "C" void kernel_launch(void* const* d_in, const int* in_sizes, int n_in,
                              void* d_out, int out_size, void* d_ws, size_t ws_size,
                              hipStream_t stream) {
    const float* x  = (const float*)d_in[0];
    const float* W  = (const float*)d_in[1];
    const float* U  = (const float*)d_in[2];
    const float* b  = (const float*)d_in[3];
    const float* W1 = (const float*)d_in[4];
    const float* b1 = (const float*)d_in[5];
    const float* W2 = (const float*)d_in[6];
    const float* b2 = (const float*)d_in[7];
    float* out = (float*)d_out;

    const int B = in_sizes[0] / (TT * 3);   // 16384

    // workspace (ints): len[B], histT[101*64]
    int* len = nullptr; int* histT = nullptr;
    const bool have_ws = (ws_size >= ((size_t)B + 101 * NCHUNK) * sizeof(int))
                         && (B % 256 == 0);
    if (have_ws) {
        len   = (int*)d_ws;
        histT = len + B;
        len_hist_kernel<<<dim3(B / 256), dim3(256), 0, stream>>>(x, len, histT, B);
    }

    lstm_kernel<<<dim3(B / NB), dim3(NTH), 0, stream>>>(
        x, W, U, b, W1, b1, W2, b2, len, histT, out, B);
}

// Round 11
// 223.457 us; speedup vs baseline: 1.1893x; 1.1893x over previous
//
#include <hip/hip_runtime.h>
#include <math.h>

#define UNITS 64
#define TT 100
#define NB 16          // batch rows per workgroup = one MFMA M-tile
#define NTH 256        // 4 waves; wave w owns unit-columns [16w,16w+16) for all 4 gates
#define HSTR 72        // hbuf row stride in halves
#define XQSTR 18       // xt quad stride per timestep (16 rows + 2 pad -> conflict-free)
#define NCHUNK 64      // prologue chunks (256 rows each); 64 blocks are always co-resident
#define FLAG_MAGIC 0x7C0FFEE1u   // != 0xAAAAAAAA poison, != 0

typedef _Float16 half8 __attribute__((ext_vector_type(8)));
typedef _Float16 half4 __attribute__((ext_vector_type(4)));
typedef float floatx4 __attribute__((ext_vector_type(4)));

#define LOG2E 1.44269504088896f

__device__ __forceinline__ float rcp_fast(float x) { return __builtin_amdgcn_rcpf(x); }
__device__ __forceinline__ float exp2_fast(float x) { return __builtin_amdgcn_exp2f(x); }

__device__ __forceinline__ float fast_sigmoid(float x) {
    return rcp_fast(1.0f + exp2_fast(-LOG2E * x));      // saturates correctly
}
__device__ __forceinline__ float fast_tanh(float x) {
    return __builtin_fmaf(2.0f, rcp_fast(1.0f + exp2_fast(-2.0f * LOG2E * x)), -1.0f);
}

// ---- single-node prologue: lengths + per-chunk hist + barrier + scatter ----
// 64 blocks (co-resident on 256 CUs -> software barrier is deadlock-free).
__global__ __launch_bounds__(256) void sort_prologue_kernel(
    const float* __restrict__ x, int* __restrict__ histT, unsigned int* __restrict__ flags,
    int* __restrict__ perm, int* __restrict__ rlen, int B)
{
    __shared__ int lh[TT + 1];     // chunk histogram
    __shared__ int llen[256];      // chunk row lengths
    __shared__ int s_hist[TT + 1]; // total histogram
    __shared__ int s_rank0[TT + 1];// offs[l] + chunk base[l] for this chunk
    __shared__ int s_cur[TT + 1];  // per-length cursor

    const int tid = threadIdx.x;
    const int bi  = blockIdx.x;
    const int grp = tid >> 4;      // row within pass
    const int sub = tid & 15;      // lane within row

    for (int i = tid; i <= TT; i += 256) { lh[i] = 0; s_cur[i] = 0; }
    __syncthreads();

    // ---- Phase A: lengths of rows [256*bi, 256*bi+256) ----
    for (int pass = 0; pass < 16; ++pass) {
        const int row = bi * 256 + pass * 16 + grp;
        const float* xp = x + (size_t)row * (TT * 3);
        int m = 0;
        for (int t = sub; t < TT; t += 16) {   // 16 lanes x 12B contiguous
            const float a = xp[3*t], b = xp[3*t+1], c = xp[3*t+2];
            if (a != 0.0f || b != 0.0f || c != 0.0f) m = t + 1;
        }
        #pragma unroll
        for (int off = 8; off; off >>= 1) m = max(m, __shfl_down(m, off, 16));
        if (sub == 0) { llen[pass * 16 + grp] = m; atomicAdd(&lh[m], 1); }  // LDS only
    }
    __syncthreads();
    for (int i = tid; i <= TT; i += 256) histT[i * NCHUNK + bi] = lh[i];

    // ---- publish + software grid barrier over 64 blocks ----
    __threadfence();               // agent-scope: drain histT writes past this XCD's L2
    __syncthreads();
    if (tid == 0)
        __hip_atomic_store(&flags[bi], FLAG_MAGIC, __ATOMIC_RELEASE, __HIP_MEMORY_SCOPE_AGENT);
    if (tid < NCHUNK) {
        while (__hip_atomic_load(&flags[tid], __ATOMIC_ACQUIRE, __HIP_MEMORY_SCOPE_AGENT)
               != FLAG_MAGIC) { }
    }
    __syncthreads();
    __threadfence();               // acquire side: invalidate stale L2 lines

    // ---- Phase B: total hist, descending offsets, chunk bases ----
    for (int i = tid; i <= TT; i += 256) {
        int s = 0, base = 0;
        for (int pb = 0; pb < NCHUNK; ++pb) {
            const int v = histT[i * NCHUNK + pb];
            s += v;
            if (pb < bi) base += v;
        }
        s_hist[i] = s;
        s_rank0[i] = base;
    }
    __syncthreads();
    for (int i = tid; i <= TT; i += 256) {
        int s = 0;
        for (int k = i + 1; k <= TT; ++k) s += s_hist[k];
        s_rank0[i] += s;           // = descending offs[l] + base of this chunk within group
    }
    __syncthreads();

    // ---- scatter own 256 rows (any order within a length group is valid) ----
    {
        const int myl = llen[tid];
        const int ord = atomicAdd(&s_cur[myl], 1);
        const int r = s_rank0[myl] + ord;
        if (r >= 0 && r < B) { perm[r] = bi * 256 + tid; rlen[r] = myl; }
    }
}

__global__ __launch_bounds__(NTH, 4) void lstm_kernel(
    const float* __restrict__ x,    // (B,100,3)
    const float* __restrict__ W,    // (3,256)
    const float* __restrict__ U,    // (64,256)
    const float* __restrict__ bias, // (256,)
    const float* __restrict__ W1,   // (64,64)
    const float* __restrict__ b1,   // (64,)
    const float* __restrict__ W2,   // (64,5)
    const float* __restrict__ b2,   // (5,)
    const int* __restrict__ perm,   // (B,) rank -> batch, descending length (may be null)
    const int* __restrict__ rlen,   // (B,) length at rank (may be null)
    float* __restrict__ out, int B)
{
    __shared__ __align__(16) _Float16 hb[2][NB * HSTR];   // double-buffered h (f16)
    __shared__ __align__(16) _Float16 xt[TT * XQSTR * 4]; // staged x tile: quads {x0,x1,x2,1}
    __shared__ __align__(16) _Float16 zq[8];              // zero quad for q!=0 AX reads
    __shared__ int shInt[2 * NB];                         // rows / lengths for this tile
    __shared__ float h1buf[NB * 64];
    __shared__ float logitbuf[NB * 5];

    const int tid = threadIdx.x;
    const int w   = tid >> 6;
    const int l   = tid & 63;
    const int q   = l >> 4;
    const int cnl = l & 15;
    const int b0  = blockIdx.x * NB;
    const int grp = tid >> 4;   // staging: row within tile
    const int sub = tid & 15;

    if (tid < NB) {
        int g = perm ? perm[b0 + tid] : (b0 + tid);
        g = (g < 0) ? 0 : ((g >= B) ? (B - 1) : g);
        shInt[tid] = g;
        int ll = rlen ? rlen[b0 + tid] : TT;
        shInt[NB + tid] = (ll < 0) ? 0 : ((ll > TT) ? TT : ll);
    }
    if (tid < 8) zq[tid] = (_Float16)0.0f;
    for (int i = tid; i < NB * HSTR; i += NTH) hb[0][i] = (_Float16)0.0f;
    __syncthreads();   // shInt visible before ANY reader (round-7 lesson)

    int maxlen = shInt[NB];               // descending sort -> rank b0 is tile max
    maxlen = (maxlen < 0) ? 0 : ((maxlen > TT) ? TT : maxlen);
    int minlen = shInt[NB + NB - 1];      // smallest length in tile
    minlen = (minlen < 0) ? 0 : ((minlen > maxlen) ? maxlen : minlen);
    int rl[4];
    #pragma unroll
    for (int r = 0; r < 4; ++r) rl[r] = shInt[NB + 4*q + r];

    // ---- stage x tile as f16 quads {x0,x1,x2,1}: row grp, steps sub..maxlen ----
    {
        const float* xp = x + (size_t)shInt[grp] * (TT * 3);
        for (int t = sub; t < maxlen; t += 16) {
            const float a = xp[3*t], b = xp[3*t+1], c = xp[3*t+2];
            half4 v = { (_Float16)a, (_Float16)b, (_Float16)c, (_Float16)1.0f };
            *(half4*)&xt[(t * XQSTR + grp) * 4] = v;
        }
    }

    // ---- one-time preload: extended-K B fragments. Rows 0..63=U, 64..66=W,
    // 67=bias, 68..95=0.  B-frag (16x16x32): lane holds B[k=32kb+8q+j][zc].
    half8 Bf[4][3];
    #pragma unroll
    for (int g = 0; g < 4; ++g) {
        const int zc = 64 * g + 16 * w + cnl;
        #pragma unroll
        for (int kb = 0; kb < 3; ++kb)
            #pragma unroll
            for (int j = 0; j < 8; ++j) {
                const int k = 32 * kb + 8 * q + j;
                float v = 0.0f;
                if (k < 64)       v = U[k * 256 + zc];
                else if (k < 67)  v = W[(k - 64) * 256 + zc];
                else if (k == 67) v = bias[zc];
                Bf[g][kb][j] = (_Float16)v;
            }
    }

    float c4[4] = {0.0f, 0.0f, 0.0f, 0.0f};
    _Float16 hcur[4] = {(_Float16)0.0f, (_Float16)0.0f, (_Float16)0.0f, (_Float16)0.0f};
    const floatx4 zero4 = {0.0f, 0.0f, 0.0f, 0.0f};

    __syncthreads();   // staging + hb[0] zero + zq visible

    int t = 0;

    // ---- unmasked main loop: all 16 rows live for t < minlen ----
    #pragma unroll 1
    for (; t < minlen; ++t) {
        const _Float16* hbc = hb[t & 1];
        _Float16*       hbn = hb[(t + 1) & 1];

        const half8 A0 = *(const half8*)&hbc[cnl * HSTR + 8 * q];
        const half8 A1 = *(const half8*)&hbc[cnl * HSTR + 32 + 8 * q];
        const _Float16* xaddr = (q == 0) ? &xt[(t * XQSTR + cnl) * 4] : zq;
        const half4 x4 = *(const half4*)xaddr;
        const half8 AX = { x4[0], x4[1], x4[2], x4[3],
                           (_Float16)0.0f, (_Float16)0.0f, (_Float16)0.0f, (_Float16)0.0f };

        floatx4 acc[4];
        #pragma unroll
        for (int g = 0; g < 4; ++g) {
            acc[g] = __builtin_amdgcn_mfma_f32_16x16x32_f16(AX, Bf[g][2], zero4, 0, 0, 0);
            acc[g] = __builtin_amdgcn_mfma_f32_16x16x32_f16(A0, Bf[g][0], acc[g], 0, 0, 0);
            acc[g] = __builtin_amdgcn_mfma_f32_16x16x32_f16(A1, Bf[g][1], acc[g], 0, 0, 0);
        }

        #pragma unroll
        for (int r = 0; r < 4; ++r) {
            const float iv = fast_sigmoid(acc[0][r]);
            const float fv = fast_sigmoid(acc[1][r]);
            const float gv = fast_tanh  (acc[2][r]);
            const float ov = fast_sigmoid(acc[3][r]);
            const float cn = fv * c4[r] + iv * gv;
            c4[r] = cn;
            hcur[r] = (_Float16)(ov * fast_tanh(cn));
            hbn[(4 * q + r) * HSTR + 16 * w + cnl] = hcur[r];
        }
        __syncthreads();
    }

    // ---- masked tail: rows die as t reaches their length ----
    #pragma unroll 1
    for (; t < maxlen; ++t) {
        const _Float16* hbc = hb[t & 1];
        _Float16*       hbn = hb[(t + 1) & 1];

        const half8 A0 = *(const half8*)&hbc[cnl * HSTR + 8 * q];
        const half8 A1 = *(const half8*)&hbc[cnl * HSTR + 32 + 8 * q];
        const _Float16* xaddr = (q == 0) ? &xt[(t * XQSTR + cnl) * 4] : zq;
        const half4 x4 = *(const half4*)xaddr;
        const half8 AX = { x4[0], x4[1], x4[2], x4[3],
                           (_Float16)0.0f, (_Float16)0.0f, (_Float16)0.0f, (_Float16)0.0f };

        floatx4 acc[4];
        #pragma unroll
        for (int g = 0; g < 4; ++g) {
            acc[g] = __builtin_amdgcn_mfma_f32_16x16x32_f16(AX, Bf[g][2], zero4, 0, 0, 0);
            acc[g] = __builtin_amdgcn_mfma_f32_16x16x32_f16(A0, Bf[g][0], acc[g], 0, 0, 0);
            acc[g] = __builtin_amdgcn_mfma_f32_16x16x32_f16(A1, Bf[g][1], acc[g], 0, 0, 0);
        }

        #pragma unroll
        for (int r = 0; r < 4; ++r) {
            const bool live = (t < rl[r]);
            const float iv = fast_sigmoid(acc[0][r]);
            const float fv = fast_sigmoid(acc[1][r]);
            const float gv = fast_tanh  (acc[2][r]);
            const float ov = fast_sigmoid(acc[3][r]);
            const float cn = fv * c4[r] + iv * gv;
            c4[r] = live ? cn : c4[r];
            const _Float16 hn = (_Float16)(ov * fast_tanh(cn));
            hcur[r] = live ? hn : hcur[r];
            hbn[(4 * q + r) * HSTR + 16 * w + cnl] = hcur[r];
        }
        __syncthreads();
    }

    const _Float16* hbL = hb[maxlen & 1];

    // ---- epilogue: h1 = relu(h @ W1 + b1) ----
    {
        const int j  = tid & 63;
        const int bb = tid >> 6;
        const float bj = b1[j];
        #pragma unroll
        for (int p = 0; p < NB / 4; ++p) {
            const int b = p * 4 + bb;
            float acc = bj;
            #pragma unroll 8
            for (int k = 0; k < UNITS; ++k)
                acc += (float)hbL[b * HSTR + k] * W1[k * 64 + j];
            h1buf[b * 64 + j] = fmaxf(acc, 0.0f);
        }
    }
    __syncthreads();

    if (tid < NB * 5) {
        const int b = tid / 5, s = tid % 5;
        float acc = b2[s];
        for (int j = 0; j < 64; ++j)
            acc += h1buf[b * 64 + j] * W2[j * 5 + s];
        logitbuf[b * 5 + s] = acc;
    }
    __syncthreads();

    if (tid < NB) {
        const int gb = shInt[tid];
        const float l0 = logitbuf[tid * 5 + 0];
        const float l1 = logitbuf[tid * 5 + 1];
        const float l2 = logitbuf[tid * 5 + 2];
        const float l3 = logitbuf[tid * 5 + 3];
        const float l4 = logitbuf[tid * 5 + 4];
        const float m  = fmaxf(fmaxf(fmaxf(l0, l1), fmaxf(l2, l3)), l4);
        const float e0 = __expf(l0 - m), e1 = __expf(l1 - m), e2 = __expf(l2 - m);
        const float e3 = __expf(l3 - m), e4 = __expf(l4 - m);
        const float rs = 1.0f / (e0 + e1 + e2 + e3 + e4);
        out[(size_t)gb * 5 + 0] = e0 * rs;
        out[(size_t)gb * 5 + 1] = e1 * rs;
        out[(size_t)gb * 5 + 2] = e2 * rs;
        out[(size_t)gb * 5 + 3] = e3 * rs;
        out[(size_t)gb * 5 + 4] = e4 * rs;
    }
}

extern "C" void kernel_launch(void* const* d_in, const int* in_sizes, int n_in,
                              void* d_out, int out_size, void* d_ws, size_t ws_size,
                              hipStream_t stream) {
    const float* x  = (const float*)d_in[0];
    const float* W  = (const float*)d_in[1];
    const float* U  = (const float*)d_in[2];
    const float* b  = (const float*)d_in[3];
    const float* W1 = (const float*)d_in[4];
    const float* b1 = (const float*)d_in[5];
    const float* W2 = (const float*)d_in[6];
    const float* b2 = (const float*)d_in[7];
    float* out = (float*)d_out;

    const int B = in_sizes[0] / (TT * 3);   // 16384

    // workspace (ints): perm[B], rlen[B], histT[101*64], flags[64]
    int* perm = nullptr; int* rlen = nullptr;
    const size_t need = ((size_t)2 * B + 101 * NCHUNK + NCHUNK) * sizeof(int);
    const bool have_ws = (ws_size >= need) && (B == NCHUNK * 256);
    if (have_ws) {
        perm                 = (int*)d_ws;
        rlen                 = perm + B;
        int* histT           = rlen + B;
        unsigned int* flags  = (unsigned int*)(histT + 101 * NCHUNK);
        sort_prologue_kernel<<<dim3(NCHUNK), dim3(256), 0, stream>>>(
            x, histT, flags, perm, rlen, B);
    }

    lstm_kernel<<<dim3(B / NB), dim3(NTH), 0, stream>>>(
        x, W, U, b, W1, b1, W2, b2, perm, rlen, out, B);
}